// Round 3
// baseline (752.964 us; speedup 1.0000x reference)
//
#include <hip/hip_runtime.h>
#include <hip/hip_bf16.h>

#define B_ 4
#define S_ 2048
#define D_ 1024
#define H_ 16
#define HD_ 64

typedef __attribute__((ext_vector_type(8))) short short8;
typedef __attribute__((ext_vector_type(4))) short short4v;
typedef __attribute__((ext_vector_type(4))) float f32x4;

__device__ inline short f2bf(float f) {
    union { __hip_bfloat16 h; short s; } u;
    u.h = __float2bfloat16(f);
    return u.s;
}

__device__ inline void gload_lds16(const void* g, void* l) {
    __builtin_amdgcn_global_load_lds(
        (const __attribute__((address_space(1))) void*)g,
        (__attribute__((address_space(3))) void*)l, 16, 0, 0);
}

// ---------------- fp32 -> bf16 cast ----------------
__global__ void cast_f32_bf16(const float* __restrict__ in, short* __restrict__ out, int n4) {
    int idx = blockIdx.x * blockDim.x + threadIdx.x;
    int stride = gridDim.x * blockDim.x;
    for (int i = idx; i < n4; i += stride) {
        float4 v = reinterpret_cast<const float4*>(in)[i];
        short4v o;
        o[0] = f2bf(v.x); o[1] = f2bf(v.y); o[2] = f2bf(v.z); o[3] = f2bf(v.w);
        reinterpret_cast<short4v*>(out)[i] = o;
    }
}

// ---------------- GEMM: C = A(MxK) * B(NxK)^T + bias, bf16 in, epilogue-templated -----
// EPI==0: scatter to q,k (B,H,S,HD) bf16 and v^T (B,H,HD,S) bf16
// EPI==1: plain fp32 store to co (M x N)
template<int EPI>
__global__ __launch_bounds__(256) void gemm_bt(
    const short* __restrict__ A, const short* __restrict__ Bm,
    const float* __restrict__ bias, int M, int N, int K,
    short* __restrict__ qo, short* __restrict__ ko, short* __restrict__ vo,
    float* __restrict__ co)
{
    __shared__ __attribute__((aligned(16))) short As[128 * 64];
    __shared__ __attribute__((aligned(16))) short Bs[128 * 64];

    const int t = threadIdx.x;
    const int wid = t >> 6, l = t & 63;
    const int wm = wid >> 1, wn = wid & 1;
    const int m0 = blockIdx.y * 128, n0 = blockIdx.x * 128;
    const int lr = l & 15, lg = l >> 4;

    f32x4 acc[4][4] = {};

    const int rowA = t >> 3;          // 0..31
    const int col8 = (t & 7) << 3;    // 0,8,...,56

    for (int k0 = 0; k0 < K; k0 += 64) {
#pragma unroll
        for (int c = 0; c < 4; ++c) {
            gload_lds16(A + (size_t)(m0 + c * 32 + rowA) * K + k0 + col8, &As[c * 2048 + t * 8]);
            gload_lds16(Bm + (size_t)(n0 + c * 32 + rowA) * K + k0 + col8, &Bs[c * 2048 + t * 8]);
        }
        __syncthreads();
#pragma unroll
        for (int kk = 0; kk < 2; ++kk) {
            short8 af[4], bfr[4];
#pragma unroll
            for (int i = 0; i < 4; ++i)
                af[i] = *(const short8*)&As[(wm * 64 + i * 16 + lr) * 64 + kk * 32 + lg * 8];
#pragma unroll
            for (int j = 0; j < 4; ++j)
                bfr[j] = *(const short8*)&Bs[(wn * 64 + j * 16 + lr) * 64 + kk * 32 + lg * 8];
#pragma unroll
            for (int i = 0; i < 4; ++i)
#pragma unroll
                for (int j = 0; j < 4; ++j)
                    acc[i][j] = __builtin_amdgcn_mfma_f32_16x16x32_bf16(af[i], bfr[j], acc[i][j], 0, 0, 0);
        }
        __syncthreads();
    }

#pragma unroll
    for (int i = 0; i < 4; ++i) {
#pragma unroll
        for (int j = 0; j < 4; ++j) {
#pragma unroll
            for (int r = 0; r < 4; ++r) {
                int gm = m0 + wm * 64 + i * 16 + lg * 4 + r;
                int gn = n0 + wn * 64 + j * 16 + lr;
                float v = acc[i][j][r] + bias[gn];
                if (EPI == 0) {
                    int which = gn >> 10, h = (gn >> 6) & 15, hd = gn & 63;
                    int b = gm >> 11, s = gm & 2047;
                    short bv = f2bf(v);
                    if (which == 0)      qo[((size_t)(b * H_ + h) * S_ + s) * HD_ + hd] = bv;
                    else if (which == 1) ko[((size_t)(b * H_ + h) * S_ + s) * HD_ + hd] = bv;
                    else                 vo[((size_t)(b * H_ + h) * HD_ + hd) * S_ + s] = bv;
                } else {
                    co[(size_t)gm * N + gn] = v;
                }
            }
        }
    }
}

// ---------------- flash attention: one (b,h), 128 q-rows per block ----------------
__global__ __launch_bounds__(256) void attn_kernel(
    const short* __restrict__ qb, const short* __restrict__ kb,
    const short* __restrict__ vtb, const float* __restrict__ bias,
    short* __restrict__ ab)
{
    __shared__ __attribute__((aligned(16))) short Ks[128 * 72];    // padded: row stride 72
    __shared__ __attribute__((aligned(16))) short Vts[64 * 136];   // V^T, padded
    __shared__ __attribute__((aligned(16))) short Pl[4 * 32 * 136];

    const int t = threadIdx.x, wid = t >> 6, l = t & 63;
    const int lr = l & 15, lg = l >> 4;
    const int q0 = blockIdx.x * 128;
    const int h = blockIdx.y >> 2, b = blockIdx.y & 3;
    const int bh = b * H_ + h;

    const short* Qbase = qb + (size_t)bh * S_ * HD_;
    const short* Kbase = kb + (size_t)bh * S_ * HD_;
    const short* Vbase = vtb + (size_t)bh * HD_ * S_;
    const float* biasH = bias + (size_t)h * S_ * S_;

    short8 qf[2][2];
#pragma unroll
    for (int i = 0; i < 2; ++i)
#pragma unroll
        for (int kk = 0; kk < 2; ++kk)
            qf[i][kk] = *(const short8*)(Qbase + (size_t)(q0 + wid * 32 + i * 16 + lr) * HD_ + kk * 32 + lg * 8);

    f32x4 o[2][4] = {};
    float m_run[2][4], l_run[2][4];
#pragma unroll
    for (int i = 0; i < 2; ++i)
#pragma unroll
        for (int r = 0; r < 4; ++r) { m_run[i][r] = -1e30f; l_run[i][r] = 0.f; }

    const int krow = t >> 3, kcol = (t & 7) << 3;    // K: 32 rows/chunk
    const int vrow = t >> 4, vcol = (t & 15) << 3;   // Vt: 16 rows/chunk

    for (int kv0 = 0; kv0 < S_; kv0 += 128) {
        // reg-stage K (128x64) and V^T (64x128) into padded LDS
        short8 kreg[4], vreg[4];
#pragma unroll
        for (int c = 0; c < 4; ++c) {
            kreg[c] = *(const short8*)(Kbase + (size_t)(kv0 + c * 32 + krow) * HD_ + kcol);
            vreg[c] = *(const short8*)(Vbase + (size_t)(c * 16 + vrow) * S_ + kv0 + vcol);
        }
#pragma unroll
        for (int c = 0; c < 4; ++c) {
            *(short8*)&Ks[(c * 32 + krow) * 72 + kcol] = kreg[c];
            *(short8*)&Vts[(c * 16 + vrow) * 136 + vcol] = vreg[c];
        }
        __syncthreads();

        // QK^T : per wave 32 q-rows x 128 kv
        f32x4 sc[2][8];
#pragma unroll
        for (int j = 0; j < 8; ++j) {
            short8 kf0 = *(const short8*)&Ks[(j * 16 + lr) * 72 + lg * 8];
            short8 kf1 = *(const short8*)&Ks[(j * 16 + lr) * 72 + 32 + lg * 8];
#pragma unroll
            for (int i = 0; i < 2; ++i) {
                f32x4 z = {};
                z = __builtin_amdgcn_mfma_f32_16x16x32_bf16(qf[i][0], kf0, z, 0, 0, 0);
                sc[i][j] = __builtin_amdgcn_mfma_f32_16x16x32_bf16(qf[i][1], kf1, z, 0, 0, 0);
            }
        }

        // bias + scale + online softmax; write P (bf16) to padded LDS
#pragma unroll
        for (int i = 0; i < 2; ++i) {
#pragma unroll
            for (int r = 0; r < 4; ++r) {
                int qrow = q0 + wid * 32 + i * 16 + lg * 4 + r;
                const float* brow = biasH + (size_t)qrow * S_ + kv0 + lr;
                float vj[8];
                float mx = -1e30f;
#pragma unroll
                for (int j = 0; j < 8; ++j) {
                    float v = sc[i][j][r] * 0.125f + brow[j * 16];
                    vj[j] = v;
                    mx = fmaxf(mx, v);
                }
#pragma unroll
                for (int d = 1; d < 16; d <<= 1)
                    mx = fmaxf(mx, __shfl_xor(mx, d));
                float mnew = fmaxf(m_run[i][r], mx);
                float fi = __expf(m_run[i][r] - mnew);
                m_run[i][r] = mnew;
                l_run[i][r] *= fi;
#pragma unroll
                for (int nf = 0; nf < 4; ++nf) o[i][nf][r] *= fi;
                float ls = 0.f;
#pragma unroll
                for (int j = 0; j < 8; ++j) {
                    float p = __expf(vj[j] - mnew);
                    ls += p;
                    Pl[wid * 4352 + (i * 16 + lg * 4 + r) * 136 + j * 16 + lr] = f2bf(p);
                }
                l_run[i][r] += ls;
            }
        }
        __syncthreads();

        // PV : O += P(32x128) * V(128x64)
#pragma unroll
        for (int kk = 0; kk < 4; ++kk) {
            short8 pa[2], vb[4];
#pragma unroll
            for (int i = 0; i < 2; ++i)
                pa[i] = *(const short8*)&Pl[wid * 4352 + (i * 16 + lr) * 136 + kk * 32 + lg * 8];
#pragma unroll
            for (int nf = 0; nf < 4; ++nf)
                vb[nf] = *(const short8*)&Vts[(nf * 16 + lr) * 136 + kk * 32 + lg * 8];
#pragma unroll
            for (int i = 0; i < 2; ++i)
#pragma unroll
                for (int nf = 0; nf < 4; ++nf)
                    o[i][nf] = __builtin_amdgcn_mfma_f32_16x16x32_bf16(pa[i], vb[nf], o[i][nf], 0, 0, 0);
        }
        __syncthreads();
    }

    // normalize + store (B,S,D) bf16
#pragma unroll
    for (int i = 0; i < 2; ++i) {
#pragma unroll
        for (int r = 0; r < 4; ++r) {
            float ls = l_run[i][r];
#pragma unroll
            for (int d = 1; d < 16; d <<= 1) ls += __shfl_xor(ls, d);
            float inv = 1.f / ls;
            int qrow = q0 + wid * 32 + i * 16 + lg * 4 + r;
#pragma unroll
            for (int nf = 0; nf < 4; ++nf)
                ab[((size_t)b * S_ + qrow) * D_ + h * HD_ + nf * 16 + lr] = f2bf(o[i][nf][r] * inv);
        }
    }
}

extern "C" void kernel_launch(void* const* d_in, const int* in_sizes, int n_in,
                              void* d_out, int out_size, void* d_ws, size_t ws_size,
                              hipStream_t stream) {
    (void)in_sizes; (void)n_in; (void)out_size; (void)ws_size;
    const float* x     = (const float*)d_in[0];
    const float* bias  = (const float*)d_in[1];
    const float* qkv_w = (const float*)d_in[2];
    const float* qkv_b = (const float*)d_in[3];
    const float* out_w = (const float*)d_in[4];
    const float* out_b = (const float*)d_in[5];
    float* out = (float*)d_out;

    char* w = (char*)d_ws;
    short* xb    = (short*)(w + 0);
    short* wqkvb = (short*)(w + (16u << 20));
    short* woutb = (short*)(w + (22u << 20));
    short* qb    = (short*)(w + (24u << 20));
    short* kb    = (short*)(w + (40u << 20));
    short* vtb   = (short*)(w + (56u << 20));
    short* ab    = (short*)(w + (72u << 20));

    cast_f32_bf16<<<2048, 256, 0, stream>>>(x, xb, (B_ * S_ * D_) / 4);
    cast_f32_bf16<<<1024, 256, 0, stream>>>(qkv_w, wqkvb, (3 * D_ * D_) / 4);
    cast_f32_bf16<<<512, 256, 0, stream>>>(out_w, woutb, (D_ * D_) / 4);

    dim3 g1(24, 64);
    gemm_bt<0><<<g1, 256, 0, stream>>>(xb, wqkvb, qkv_b, B_ * S_, 3 * D_, D_,
                                       qb, kb, vtb, nullptr);

    dim3 ga(16, B_ * H_);
    attn_kernel<<<ga, 256, 0, stream>>>(qb, kb, vtb, bias, ab);

    dim3 g2(8, 64);
    gemm_bt<1><<<g2, 256, 0, stream>>>(ab, woutb, out_b, B_ * S_, D_, D_,
                                       nullptr, nullptr, nullptr, out);
}